// Round 1
// baseline (316.408 us; speedup 1.0000x reference)
//
#include <hip/hip_runtime.h>
#include <hip/hip_bf16.h>

// MonarchOutProjection: out[t][r*32+q] = sum_p R[q][r][p] * sum_m L[p][q][m] * x[t][m*32+p]
// Round 3: latency-serialization fix (prev: VGPR=52 => zero hoisting; all pipes <30%).
//  - persistent: 512 blocks x 4 tiles of 16 tokens, 2 blocks/CU (64 KiB LDS, ~200 VGPR).
//  - R-frags resident in regs; L-frags streamed per tile (issued a full phase early).
//  - x(i+1) prefetched into 64 VGPRs during stage2(i); raw s_barrier + lgkmcnt-only
//    fences keep those loads in flight across barriers (no vmcnt(0) drain).
//  - two LDS buffers: bufX (x, then y2) / bufY (y1) -> no read/write aliasing,
//    batched reads-then-MFMA-then-writes everywhere.
//  - swizzle el ^ (t<<2): every access class spreads over 16 banks (<=4-way).
//  - y1 writes vectorized (ds_write_b64) via bufY layout [t][p*32+q].

typedef __attribute__((ext_vector_type(8))) short short8;
typedef __attribute__((ext_vector_type(4))) float floatx4;

__device__ __forceinline__ unsigned int pack2bf(float a, float b) {
    __hip_bfloat162 h = __float22bfloat162_rn(float2{a, b});  // packed cvt
    return *(unsigned int*)&h;
}

// Barrier with LDS-only drain: do NOT drain vmcnt (keeps x-prefetch in flight).
__device__ __forceinline__ void block_sync() {
    asm volatile("s_waitcnt lgkmcnt(0)" ::: "memory");
    __builtin_amdgcn_s_barrier();
    asm volatile("" ::: "memory");   // no LDS op hoists above the barrier
}

// Lb[(p*2+qt)*64 + lane] (short8) = L[p][q=qt*16+(lane&15)][m=(lane>>4)*8 .. +8] as bf16.
// Same for Rb. 8192 threads, one short8 each. (unchanged from round 2)
__global__ void prep_weights(const float* __restrict__ L, const float* __restrict__ R,
                             unsigned short* __restrict__ Lb, unsigned short* __restrict__ Rb) {
    const int t = blockIdx.x * 256 + threadIdx.x;          // 0..8191
    const float* src        = (t < 4096) ? L : R;
    unsigned short* dst     = (t < 4096) ? Lb : Rb;
    const int i    = t & 4095;                             // (p*2+qt)*64 + lane
    const int lane = i & 63;
    const int pq   = i >> 6;
    const int p    = pq >> 1;
    const int qt   = pq & 1;
    const int q    = qt * 16 + (lane & 15);
    const int m0   = (lane >> 4) * 8;
    const float* s = src + (p * 32 + q) * 32 + m0;
    uint4 o;
    o.x = pack2bf(s[0], s[1]);
    o.y = pack2bf(s[2], s[3]);
    o.z = pack2bf(s[4], s[5]);
    o.w = pack2bf(s[6], s[7]);
    *(uint4*)(dst + (size_t)i * 8) = o;
}

#define TILES 4

__global__ __launch_bounds__(256, 2)
void monarch_kernel(const float* __restrict__ x,
                    const unsigned short* __restrict__ Lb,
                    const unsigned short* __restrict__ Rb,
                    float* __restrict__ out) {
    // bufX: x tile (bf16), later reused for y2.  bufY: y1 as [t][p*32+q].
    // Swizzle: element el of row t lives at index el ^ (t<<2) (bits 2..5 -> 16-bank
    // spread on scalar reads/writes; preserves 4-element alignment for b64 ops).
    __shared__ __align__(16) unsigned short bufX[16][1024];   // 32 KiB
    __shared__ __align__(16) unsigned short bufY[16][1024];   // 32 KiB

    const int tid  = threadIdx.x;
    const int w    = tid >> 6;
    const int lane = tid & 63;
    const int tl   = lane & 15;       // token row / MFMA col
    const int quad = lane >> 4;
    const int c    = tid * 4;         // stage-in / dump channel base

    // ---- R fragments: tile-invariant, keep resident all kernel (64 VGPR) ----
    short8 ra[8][2];
    #pragma unroll
    for (int qq = 0; qq < 8; ++qq) {
        const int q = w * 8 + qq;
        ra[qq][0] = *(const short8*)(Rb + (size_t)((q * 2 + 0) * 64 + lane) * 8);
        ra[qq][1] = *(const short8*)(Rb + (size_t)((q * 2 + 1) * 64 + lane) * 8);
    }

    const long tile0 = (long)blockIdx.x * TILES;

    // ---- prefetch tile 0 x into registers ----
    float4 xr[16];
    {
        const long tok0 = tile0 * 16;
        #pragma unroll
        for (int t = 0; t < 16; ++t)
            xr[t] = *(const float4*)(x + (tok0 + t) * 1024 + c);
    }

    for (int it = 0; it < TILES; ++it) {
        const long tok0 = (tile0 + it) * 16;

        // L fragments streamed: issued here, first used after barrier A + 64 ds_reads
        // (~400 cyc of lead covers L2 latency).
        short8 la[8][2];
        #pragma unroll
        for (int pp = 0; pp < 8; ++pp) {
            const int p = w * 8 + pp;
            la[pp][0] = *(const short8*)(Lb + (size_t)((p * 2 + 0) * 64 + lane) * 8);
            la[pp][1] = *(const short8*)(Lb + (size_t)((p * 2 + 1) * 64 + lane) * 8);
        }

        // ---------- stage-in: prefetched x -> bufX (bf16, b64 writes) ----------
        #pragma unroll
        for (int t = 0; t < 16; ++t) {
            const unsigned long long v =
                ((unsigned long long)pack2bf(xr[t].z, xr[t].w) << 32) | pack2bf(xr[t].x, xr[t].y);
            *(unsigned long long*)&bufX[t][c ^ (t << 2)] = v;
        }
        block_sync();   // A

        // ---------- stage 1: batched reads, then MFMAs, then b64 y1 writes ----------
        short8 b1[8];
        #pragma unroll
        for (int pp = 0; pp < 8; ++pp) {
            const int p = w * 8 + pp;
            #pragma unroll
            for (int j = 0; j < 8; ++j)          // b1[j] = x[tl][(quad*8+j)*32 + p]
                b1[pp][j] = (short)bufX[tl][(quad * 256 + j * 32 + p) ^ (tl << 2)];
        }
        #pragma unroll
        for (int pp = 0; pp < 8; ++pp) {
            const int p = w * 8 + pp;
            #pragma unroll
            for (int qt = 0; qt < 2; ++qt) {
                floatx4 acc = {0.f, 0.f, 0.f, 0.f};
                acc = __builtin_amdgcn_mfma_f32_16x16x32_bf16(la[pp][qt], b1[pp], acc, 0, 0, 0);
                // lane holds y1[q = qt*16+quad*4 + 0..3][t=tl] for this p:
                // consecutive q in bufY layout [t][p*32+q] -> one ds_write_b64.
                const unsigned long long v =
                    ((unsigned long long)pack2bf(acc[2], acc[3]) << 32) | pack2bf(acc[0], acc[1]);
                const int el = p * 32 + qt * 16 + quad * 4;
                *(unsigned long long*)&bufY[tl][el ^ (tl << 2)] = v;
            }
        }
        block_sync();   // B

        // ---------- stage 2: batched reads ----------
        short8 b2[8];
        #pragma unroll
        for (int qq = 0; qq < 8; ++qq) {
            const int q = w * 8 + qq;
            #pragma unroll
            for (int j = 0; j < 8; ++j)          // b2[j] = y1[tl][p=quad*8+j][q]
                b2[qq][j] = (short)bufY[tl][((quad * 8 + j) * 32 + q) ^ (tl << 2)];
        }
        // prefetch x for tile it+1 now; lands during stage2 MFMAs + dump (~800 cyc).
        if (it + 1 < TILES) {
            const long ntok0 = (tile0 + it + 1) * 16;
            #pragma unroll
            for (int t = 0; t < 16; ++t)
                xr[t] = *(const float4*)(x + (ntok0 + t) * 1024 + c);
        }
        // stage 2 MFMAs (ra already resident) + y2 -> bufX[t][r*32+q]
        // (bufX is dead: all stage-1 reads completed before barrier B)
        #pragma unroll
        for (int qq = 0; qq < 8; ++qq) {
            const int q = w * 8 + qq;
            #pragma unroll
            for (int rt = 0; rt < 2; ++rt) {
                floatx4 z = {0.f, 0.f, 0.f, 0.f};
                const floatx4 acc =
                    __builtin_amdgcn_mfma_f32_16x16x32_bf16(ra[qq][rt], b2[qq], z, 0, 0, 0);
                const unsigned int lo = pack2bf(acc[0], acc[1]);
                const unsigned int hi = pack2bf(acc[2], acc[3]);
                const int r0 = rt * 16 + quad * 4;
                bufX[tl][((r0    ) * 32 + q) ^ (tl << 2)] = (unsigned short)lo;
                bufX[tl][((r0 + 1) * 32 + q) ^ (tl << 2)] = (unsigned short)(lo >> 16);
                bufX[tl][((r0 + 2) * 32 + q) ^ (tl << 2)] = (unsigned short)hi;
                bufX[tl][((r0 + 3) * 32 + q) ^ (tl << 2)] = (unsigned short)(hi >> 16);
            }
        }
        block_sync();   // C

        // ---------- dump: bufX -> out, b64 LDS reads + coalesced float4 stores ----------
        #pragma unroll
        for (int t = 0; t < 16; ++t) {
            const unsigned long long v = *(const unsigned long long*)&bufX[t][c ^ (t << 2)];
            const unsigned int lo = (unsigned int)v;
            const unsigned int hi = (unsigned int)(v >> 32);
            float4 o;
            o.x = __uint_as_float(lo << 16);
            o.y = __uint_as_float(lo & 0xffff0000u);
            o.z = __uint_as_float(hi << 16);
            o.w = __uint_as_float(hi & 0xffff0000u);
            *(float4*)(out + (tok0 + t) * 1024 + c) = o;
        }
        block_sync();   // D: all dump reads done before next tile's stage-in writes
    }
}

extern "C" void kernel_launch(void* const* d_in, const int* in_sizes, int n_in,
                              void* d_out, int out_size, void* d_ws, size_t ws_size,
                              hipStream_t stream) {
    const float* x = (const float*)d_in[0];   // (8, 4096, 1024) fp32
    const float* L = (const float*)d_in[1];   // (32, 32, 32) fp32
    const float* R = (const float*)d_in[2];   // (32, 32, 32) fp32
    float* out = (float*)d_out;

    unsigned short* Lb = (unsigned short*)d_ws;          // 32768 bf16 = 64 KiB
    unsigned short* Rb = Lb + 32768;                     // 32768 bf16 = 64 KiB

    prep_weights<<<32, 256, 0, stream>>>(L, R, Lb, Rb);  // L2-resident after

    // 32768 tokens / 16 per tile / 4 tiles per block = 512 blocks = 2 per CU.
    monarch_kernel<<<512, 256, 0, stream>>>(x, Lb, Rb, out);
}

// Round 2
// 243.441 us; speedup vs baseline: 1.2997x; 1.2997x over previous
//
#include <hip/hip_runtime.h>
#include <hip/hip_bf16.h>

// MonarchOutProjection: out[t][r*32+q] = sum_p R[q][r][p] * sum_m L[p][q][m] * x[t][m*32+p]
// Round 4: round-3 ILP structure minus the register overcommit (r3 spilled:
// VGPR demand ~200 vs cap 128 -> ~240 MB scratch traffic, dur 87->175us).
//  - 2048 blocks x 1 tile (16 tokens); no persistence, no x-prefetch array.
//  - single 32 KiB LDS buffer; in-place WAR hazards removed by batched reads
//    + an extra lgkm-only barrier between read and write phases of each stage.
//  - sequential weight residency: la (64 VGPR) issued at top overlapping the x
//    HBM loads, dies in stage-1 MFMAs; ra (64 VGPR) issued after stage-1, used
//    in stage-2. Peak live ~150 VGPR; __launch_bounds__(256,3) caps at ~170
//    -> 3 blocks/CU (12 waves/CU), no spills.
//  - barriers never drain vmcnt (raw s_barrier + lgkmcnt(0)), so weight/x loads
//    stay in flight across them.
//  - swizzle el ^ (t<<2): bits 2..5 only (preserves b64 quads), <=4-way banks.

typedef __attribute__((ext_vector_type(8))) short short8;
typedef __attribute__((ext_vector_type(4))) float floatx4;

__device__ __forceinline__ unsigned int pack2bf(float a, float b) {
    __hip_bfloat162 h = __float22bfloat162_rn(float2{a, b});  // packed cvt
    return *(unsigned int*)&h;
}

// Barrier with LDS-only drain: do NOT drain vmcnt (keeps global loads in flight).
__device__ __forceinline__ void block_sync() {
    asm volatile("s_waitcnt lgkmcnt(0)" ::: "memory");
    __builtin_amdgcn_s_barrier();
    asm volatile("" ::: "memory");
}

// Lb[(p*2+qt)*64 + lane] (short8) = L[p][q=qt*16+(lane&15)][m=(lane>>4)*8 .. +8] as bf16.
// Same for Rb. 8192 threads, one short8 each. (unchanged)
__global__ void prep_weights(const float* __restrict__ L, const float* __restrict__ R,
                             unsigned short* __restrict__ Lb, unsigned short* __restrict__ Rb) {
    const int t = blockIdx.x * 256 + threadIdx.x;          // 0..8191
    const float* src        = (t < 4096) ? L : R;
    unsigned short* dst     = (t < 4096) ? Lb : Rb;
    const int i    = t & 4095;                             // (p*2+qt)*64 + lane
    const int lane = i & 63;
    const int pq   = i >> 6;
    const int p    = pq >> 1;
    const int qt   = pq & 1;
    const int q    = qt * 16 + (lane & 15);
    const int m0   = (lane >> 4) * 8;
    const float* s = src + (p * 32 + q) * 32 + m0;
    uint4 o;
    o.x = pack2bf(s[0], s[1]);
    o.y = pack2bf(s[2], s[3]);
    o.z = pack2bf(s[4], s[5]);
    o.w = pack2bf(s[6], s[7]);
    *(uint4*)(dst + (size_t)i * 8) = o;
}

__global__ __launch_bounds__(256, 3)
void monarch_kernel(const float* __restrict__ x,
                    const unsigned short* __restrict__ Lb,
                    const unsigned short* __restrict__ Rb,
                    float* __restrict__ out) {
    // One buffer, three logical lives: x (channel layout m*32+p), y1 ([p*32+q]),
    // y2 ([r*32+q] == output channel layout). Element el of row t lives at
    // el ^ (t<<2): XOR bits 2..5 -> 16-bank spread, b64 alignment preserved.
    __shared__ __align__(16) unsigned short buf[16][1024];   // 32 KiB

    const int tid  = threadIdx.x;
    const int w    = tid >> 6;
    const int lane = tid & 63;
    const int tl   = lane & 15;       // token row / MFMA col
    const int quad = lane >> 4;
    const int c    = tid * 4;         // stage-in / dump channel base
    const long tok0 = (long)blockIdx.x * 16;

    // ---------- phase 0: issue x loads (HBM) first, then la loads (L2) ----------
    float4 xv[16];
    #pragma unroll
    for (int t = 0; t < 16; ++t)
        xv[t] = *(const float4*)(x + (tok0 + t) * 1024 + c);

    short8 la[8][2];
    #pragma unroll
    for (int pp = 0; pp < 8; ++pp) {
        const int p = w * 8 + pp;
        la[pp][0] = *(const short8*)(Lb + (size_t)((p * 2 + 0) * 64 + lane) * 8);
        la[pp][1] = *(const short8*)(Lb + (size_t)((p * 2 + 1) * 64 + lane) * 8);
    }

    // stage-in: x -> buf (bf16, b64 writes)
    #pragma unroll
    for (int t = 0; t < 16; ++t) {
        const unsigned long long v =
            ((unsigned long long)pack2bf(xv[t].z, xv[t].w) << 32) | pack2bf(xv[t].x, xv[t].y);
        *(unsigned long long*)&buf[t][c ^ (t << 2)] = v;
    }
    block_sync();   // A: stage-in writes visible

    // ---------- stage 1 reads (batched; all waves finish before any y1 write) ----------
    short8 b1[8];
    #pragma unroll
    for (int pp = 0; pp < 8; ++pp) {
        const int p = w * 8 + pp;
        #pragma unroll
        for (int j = 0; j < 8; ++j)          // b1[j] = x[tl][m=quad*8+j][p]
            b1[pp][j] = (short)buf[tl][(quad * 256 + j * 32 + p) ^ (tl << 2)];
    }
    block_sync();   // B: all x reads done -> buffer reusable for y1

    // ---------- stage 1 MFMAs + b64 y1 writes ----------
    #pragma unroll
    for (int pp = 0; pp < 8; ++pp) {
        const int p = w * 8 + pp;
        #pragma unroll
        for (int qt = 0; qt < 2; ++qt) {
            floatx4 acc = {0.f, 0.f, 0.f, 0.f};
            acc = __builtin_amdgcn_mfma_f32_16x16x32_bf16(la[pp][qt], b1[pp], acc, 0, 0, 0);
            // lane holds y1[q = qt*16+quad*4 + 0..3][t=tl]; layout [t][p*32+q]
            // makes the 4 consecutive q one ds_write_b64.
            const unsigned long long v =
                ((unsigned long long)pack2bf(acc[2], acc[3]) << 32) | pack2bf(acc[0], acc[1]);
            const int el = p * 32 + qt * 16 + quad * 4;
            *(unsigned long long*)&buf[tl][el ^ (tl << 2)] = v;
        }
    }

    // ra issued here: la is dead (consumed above), ra lands during barrier C +
    // the 64 b2 reads (~500 cyc lead over first stage-2 MFMA).
    short8 ra[8][2];
    #pragma unroll
    for (int qq = 0; qq < 8; ++qq) {
        const int q = w * 8 + qq;
        ra[qq][0] = *(const short8*)(Rb + (size_t)((q * 2 + 0) * 64 + lane) * 8);
        ra[qq][1] = *(const short8*)(Rb + (size_t)((q * 2 + 1) * 64 + lane) * 8);
    }
    block_sync();   // C: y1 writes visible

    // ---------- stage 2 reads (batched) ----------
    short8 b2[8];
    #pragma unroll
    for (int qq = 0; qq < 8; ++qq) {
        const int q = w * 8 + qq;
        #pragma unroll
        for (int j = 0; j < 8; ++j)          // b2[j] = y1[tl][p=quad*8+j][q]
            b2[qq][j] = (short)buf[tl][((quad * 8 + j) * 32 + q) ^ (tl << 2)];
    }
    block_sync();   // D: all y1 reads done -> buffer reusable for y2

    // ---------- stage 2 MFMAs + y2 writes ----------
    #pragma unroll
    for (int qq = 0; qq < 8; ++qq) {
        const int q = w * 8 + qq;
        #pragma unroll
        for (int rt = 0; rt < 2; ++rt) {
            floatx4 z = {0.f, 0.f, 0.f, 0.f};
            const floatx4 acc =
                __builtin_amdgcn_mfma_f32_16x16x32_bf16(ra[qq][rt], b2[qq], z, 0, 0, 0);
            const unsigned int lo = pack2bf(acc[0], acc[1]);
            const unsigned int hi = pack2bf(acc[2], acc[3]);
            const int r0 = rt * 16 + quad * 4;
            buf[tl][((r0    ) * 32 + q) ^ (tl << 2)] = (unsigned short)lo;
            buf[tl][((r0 + 1) * 32 + q) ^ (tl << 2)] = (unsigned short)(lo >> 16);
            buf[tl][((r0 + 2) * 32 + q) ^ (tl << 2)] = (unsigned short)hi;
            buf[tl][((r0 + 3) * 32 + q) ^ (tl << 2)] = (unsigned short)(hi >> 16);
        }
    }
    block_sync();   // E: y2 writes visible

    // ---------- dump: buf -> out, b64 LDS reads + coalesced float4 stores ----------
    #pragma unroll
    for (int t = 0; t < 16; ++t) {
        const unsigned long long v = *(const unsigned long long*)&buf[t][c ^ (t << 2)];
        const unsigned int lo = (unsigned int)v;
        const unsigned int hi = (unsigned int)(v >> 32);
        float4 o;
        o.x = __uint_as_float(lo << 16);
        o.y = __uint_as_float(lo & 0xffff0000u);
        o.z = __uint_as_float(hi << 16);
        o.w = __uint_as_float(hi & 0xffff0000u);
        *(float4*)(out + (tok0 + t) * 1024 + c) = o;
    }
}

extern "C" void kernel_launch(void* const* d_in, const int* in_sizes, int n_in,
                              void* d_out, int out_size, void* d_ws, size_t ws_size,
                              hipStream_t stream) {
    const float* x = (const float*)d_in[0];   // (8, 4096, 1024) fp32
    const float* L = (const float*)d_in[1];   // (32, 32, 32) fp32
    const float* R = (const float*)d_in[2];   // (32, 32, 32) fp32
    float* out = (float*)d_out;

    unsigned short* Lb = (unsigned short*)d_ws;          // 32768 bf16 = 64 KiB
    unsigned short* Rb = Lb + 32768;                     // 32768 bf16 = 64 KiB

    prep_weights<<<32, 256, 0, stream>>>(L, R, Lb, Rb);  // L2-resident after

    const int n_tokens = 8 * 4096;
    const int grid = n_tokens / 16;                      // 2048 blocks x 16 tokens
    monarch_kernel<<<grid, 256, 0, stream>>>(x, Lb, Rb, out);
}